// Round 15
// baseline (337.481 us; speedup 1.0000x reference)
//
#include <hip/hip_runtime.h>

typedef __bf16 bf16x8 __attribute__((ext_vector_type(8)));
typedef float f32x4 __attribute__((ext_vector_type(4)));

static __device__ __forceinline__ unsigned short f2bf(float f) {
    unsigned u = __builtin_bit_cast(unsigned, f);
    u += 0x7FFFu + ((u >> 16) & 1u);
    return (unsigned short)(u >> 16);
}
static __device__ __forceinline__ float bf2f(unsigned short h) {
    return __builtin_bit_cast(float, ((unsigned)h) << 16);
}

// async 16B global->LDS (linear LDS dest: wave-uniform base + lane*16)
#define GLOAD_LDS16(g, l)                                              \
    __builtin_amdgcn_global_load_lds(                                  \
        (const __attribute__((address_space(1))) unsigned int*)(g),    \
        (__attribute__((address_space(3))) unsigned int*)(l), 16, 0, 0)

// ---------------------------------------------------------------- fused prep
// blocks [0,HB) hist | [HB, HB+CB) cvt | [HB+CB, HB+CB+144) wbt (tiled transpose)
__global__ __launch_bounds__(256) void rgcn_prep(const int* __restrict__ ei,
                                                 unsigned* __restrict__ cnt,
                                                 const float* __restrict__ x,
                                                 unsigned short* __restrict__ Z,
                                                 const float* __restrict__ w,
                                                 const float* __restrict__ lw,
                                                 unsigned short* __restrict__ wbT,
                                                 int E, int M, int HB, int CB) {
    __shared__ float tile[64][65];
    const int b = blockIdx.x;
    const int t = threadIdx.x;
    if (b < HB) {                     // ---- histogram of dst
        int e = b * 256 + t;
        if (e < E) atomicAdd(&cnt[ei[E + e]], 1u);
    } else if (b < HB + CB) {         // ---- bf16 x -> Zcat[:, 2048:2304]
        int wv = ((b - HB) * 256 + t) >> 6;
        int lane = t & 63;
        if (wv < M) {
            float4 v = *(const float4*)(x + (size_t)wv * 256 + lane * 4);
            ushort4 o;
            o.x = f2bf(v.x); o.y = f2bf(v.y); o.z = f2bf(v.z); o.w = f2bf(v.w);
            *(ushort4*)(Z + (size_t)wv * 2304 + 2048 + lane * 4) = o;
        }
    } else {                          // ---- wbT 64x64 tile transpose (144 blocks)
        const int bb = b - HB - CB;
        const float* src;
        int kt, nt_, kcb;
        if (bb < 128) {               // weight[r]: 16 tiles each
            int r = bb >> 4, tl = bb & 15;
            kt = (tl >> 2) * 64; nt_ = (tl & 3) * 64;
            src = w + (size_t)r * 65536;
            kcb = r * 256 + kt;
        } else {                      // loop_w: 16 tiles
            int tl = bb - 128;
            kt = (tl >> 2) * 64; nt_ = (tl & 3) * 64;
            src = lw;
            kcb = 2048 + kt;
        }
        // coalesced load: 64 rows (k) x 64 cols (n)
        {
            int row = t >> 4, c4 = (t & 15) * 4;
            #pragma unroll
            for (int p = 0; p < 4; ++p) {
                int rr = row + p * 16;
                float4 v = *(const float4*)(src + (size_t)(kt + rr) * 256 + nt_ + c4);
                tile[rr][c4] = v.x; tile[rr][c4 + 1] = v.y;
                tile[rr][c4 + 2] = v.z; tile[rr][c4 + 3] = v.w;
            }
        }
        __syncthreads();
        // coalesced write: 64 rows (n) x 64 cols (kc), 16 kc per thread
        {
            const float s = 0.70710678118654752f;
            int nn = t >> 2, ko = (t & 3) * 16;
            unsigned short* dst = wbT + (size_t)(nt_ + nn) * 2304 + kcb + ko;
            #pragma unroll
            for (int q = 0; q < 4; ++q) {
                ushort4 o_;
                o_.x = f2bf(tile[ko + q * 4 + 0][nn] * s);
                o_.y = f2bf(tile[ko + q * 4 + 1][nn] * s);
                o_.z = f2bf(tile[ko + q * 4 + 2][nn] * s);
                o_.w = f2bf(tile[ko + q * 4 + 3][nn] * s);
                *(ushort4*)(dst + q * 4) = o_;
            }
        }
    }
}

// ---------------------------------------------------------------- scan + scatter
// 49 co-resident blocks. Phase A: hierarchical exclusive scan (device-scope
// atomics + spin). Phase B: after second device barrier, grid-stride scatter.
__global__ __launch_bounds__(1024) void rgcn_scan_scatter(
    const unsigned* __restrict__ cnt,
    unsigned* __restrict__ off,
    unsigned* __restrict__ cur,
    unsigned* __restrict__ done,
    unsigned* __restrict__ done2,
    unsigned* __restrict__ bsum,
    const int* __restrict__ ei,
    const int* __restrict__ et,
    unsigned* __restrict__ recs,
    int n, int nb, int E)
{
    __shared__ unsigned wsum[16];
    __shared__ unsigned bpre_s;
    const int t = threadIdx.x, lane = t & 63, wv = t >> 6;
    const int b = blockIdx.x;
    int i = b * 1024 + t;
    unsigned v = (i < n) ? cnt[i] : 0;
    unsigned s = v;
    #pragma unroll
    for (int d = 1; d < 64; d <<= 1) {
        unsigned u = __shfl_up(s, d, 64);
        if (lane >= d) s += u;
    }
    if (lane == 63) wsum[wv] = s;
    __syncthreads();
    if (wv == 0) {
        unsigned bb = (lane < 16) ? wsum[lane] : 0;
        unsigned sb = bb;
        #pragma unroll
        for (int d = 1; d < 16; d <<= 1) {
            unsigned u = __shfl_up(sb, d, 64);
            if (lane >= d) sb += u;
        }
        if (lane < 16) wsum[lane] = sb - bb;       // exclusive wave prefix
        if (lane == 15) {                          // post block total (release)
            atomicExch(&bsum[b], sb);
            __threadfence();
            atomicAdd(done, 1u);
        }
    }
    __syncthreads();
    if (t == 0) {                                  // spin until all blocks posted
        while (atomicAdd(done, 0u) < (unsigned)nb) __builtin_amdgcn_s_sleep(8);
    }
    __syncthreads();
    if (wv == 0) {                                 // cross-block exclusive prefix
        unsigned bv = (lane < nb) ? atomicAdd(&bsum[lane], 0u) : 0;
        unsigned sp = bv;
        #pragma unroll
        for (int d = 1; d < 64; d <<= 1) {
            unsigned u = __shfl_up(sp, d, 64);
            if (lane >= d) sp += u;
        }
        if (lane == b) bpre_s = sp - bv;
        if (b == 0 && lane == nb - 1) off[n] = sp; // grand total = E
    }
    __syncthreads();
    unsigned base = bpre_s + wsum[wv];
    if (i < n) {
        unsigned o = base + (s - v);
        off[i] = o;
        atomicExch(&cur[i], o);                    // device-visible cursor init
    }
    __threadfence();
    __syncthreads();
    if (t == 0) atomicAdd(done2, 1u);
    if (t == 0) {
        while (atomicAdd(done2, 0u) < (unsigned)nb) __builtin_amdgcn_s_sleep(8);
    }
    __syncthreads();

    // ---- phase B: scatter (grid-stride, 4-deep independent atomics)
    const int nt = nb * 1024;
    int e = b * 1024 + t;
    for (; e + 3 * nt < E; e += 4 * nt) {
        int d0 = ei[E + e], d1 = ei[E + e + nt], d2 = ei[E + e + 2 * nt], d3 = ei[E + e + 3 * nt];
        unsigned p0 = atomicAdd(&cur[d0], 1u);
        unsigned p1 = atomicAdd(&cur[d1], 1u);
        unsigned p2 = atomicAdd(&cur[d2], 1u);
        unsigned p3 = atomicAdd(&cur[d3], 1u);
        recs[p0] = (unsigned)ei[e]          | ((unsigned)et[e] << 16);
        recs[p1] = (unsigned)ei[e + nt]     | ((unsigned)et[e + nt] << 16);
        recs[p2] = (unsigned)ei[e + 2 * nt] | ((unsigned)et[e + 2 * nt] << 16);
        recs[p3] = (unsigned)ei[e + 3 * nt] | ((unsigned)et[e + 3 * nt] << 16);
    }
    for (; e < E; e += nt) {
        int dst = ei[E + e];
        unsigned p = atomicAdd(&cur[dst], 1u);
        recs[p] = (unsigned)ei[e] | ((unsigned)et[e] << 16);
    }
}

// ---------------------------------------------------------------- aggregation
// one wave per dst node (grid-stride). Lane l loads recs[o0+l]; per-edge records
// via __shfl; ushort4 gathers in 16-deep batches. (127us, throughput-pinned at
// ~3.1 TB/s across 4 structural variants — structural limit.)
__global__ __launch_bounds__(256) void rgcn_agg(const unsigned* __restrict__ recs,
                                                const unsigned* __restrict__ off,
                                                unsigned short* __restrict__ Z, int M) {
    const int gw0  = (blockIdx.x * 256 + threadIdx.x) >> 6;
    const int nw   = (gridDim.x * 256) >> 6;
    const int lane = threadIdx.x & 63;
    const unsigned short* Zx = Z + 2048 + lane * 4;   // gather base (x cols)

#define GATHER(rr) (*(const ushort4*)(Zx + (size_t)((rr) & 0xFFFFu) * 2304))
#define ACCUM(rec, v_)                                                                 \
    {                                                                                  \
        f32x4 fv;                                                                      \
        fv[0] = bf2f(v_.x); fv[1] = bf2f(v_.y); fv[2] = bf2f(v_.z); fv[3] = bf2f(v_.w);\
        switch ((rec) >> 16) {                                                         \
            case 0: a0 += fv; break; case 1: a1 += fv; break;                          \
            case 2: a2 += fv; break; case 3: a3 += fv; break;                          \
            case 4: a4 += fv; break; case 5: a5 += fv; break;                          \
            case 6: a6 += fv; break; default: a7 += fv; break;                         \
        }                                                                              \
    }

    for (int w = gw0; w < M; w += nw) {
        const unsigned o0 = off[w], o1 = off[w + 1];
        f32x4 a0 = {}, a1 = {}, a2 = {}, a3 = {}, a4 = {}, a5 = {}, a6 = {}, a7 = {};

        for (unsigned base = o0; base < o1; base += 64) {
            const unsigned wdeg = (o1 - base < 64u) ? (o1 - base) : 64u;
            const unsigned myrec = ((unsigned)lane < wdeg) ? recs[base + lane] : 0u;

            unsigned j = 0;
            for (; j + 16 <= wdeg; j += 16) {
                unsigned rr[16];
                #pragma unroll
                for (int u = 0; u < 16; ++u) rr[u] = __shfl(myrec, (int)(j + u), 64);
                ushort4 vv[16];
                #pragma unroll
                for (int u = 0; u < 16; ++u) vv[u] = GATHER(rr[u]);
                #pragma unroll
                for (int u = 0; u < 16; ++u) ACCUM(rr[u], vv[u]);
            }
            for (; j + 4 <= wdeg; j += 4) {
                unsigned rr[4];
                #pragma unroll
                for (int u = 0; u < 4; ++u) rr[u] = __shfl(myrec, (int)(j + u), 64);
                ushort4 vv[4];
                #pragma unroll
                for (int u = 0; u < 4; ++u) vv[u] = GATHER(rr[u]);
                #pragma unroll
                for (int u = 0; u < 4; ++u) ACCUM(rr[u], vv[u]);
            }
            for (; j < wdeg; ++j) {
                unsigned r_ = __shfl(myrec, (int)j, 64);
                ushort4 v_ = GATHER(r_);
                ACCUM(r_, v_);
            }
        }

        unsigned short* zr = Z + (size_t)w * 2304 + lane * 4;
#define ST(rr_, ax)                                                                    \
        {                                                                              \
            ushort4 o_;                                                                \
            o_.x = f2bf(ax[0]); o_.y = f2bf(ax[1]);                                    \
            o_.z = f2bf(ax[2]); o_.w = f2bf(ax[3]);                                    \
            *(ushort4*)(zr + rr_ * 256) = o_;                                          \
        }
        ST(0, a0) ST(1, a1) ST(2, a2) ST(3, a3) ST(4, a4) ST(5, a5) ST(6, a6) ST(7, a7)
#undef ST
    }
#undef GATHER
#undef ACCUM
}

// ---------------------------------------------------------------- GEMM v5 (round-12 verified)
// out[M x 256] = Zcat[M x 2304] @ wbT^T + bias
// 128x256 tile, 512 threads (8 waves, 64x64 each). LDS 64KB = A dbuf 2x16KB +
// B single 32KB -> 2 resident blocks/CU. Counted-vmcnt pipeline:
//   compute(t) -> bar -> stage B(t+1)(L2,4ld) + A(t+2)(HBM,2ld) -> vmcnt(2) -> bar
#define BM 128
#define BK 64
#define NCH 36   // 2304 / 64

__global__ __launch_bounds__(512, 4) void rgcn_gemm(
    const unsigned short* __restrict__ A,    // Zcat [M][2304]
    const unsigned short* __restrict__ Bt,   // wbT  [256][2304]
    float* __restrict__ out,                 // [M][256]
    const float* __restrict__ bias,          // [256]
    int M)
{
    __shared__ char lds[16384 * 2 + 32768];  // A0 | A1 | B
    char* Ab0 = lds;
    char* Ab1 = lds + 16384;
    char* Bb  = lds + 32768;

    const int tid  = threadIdx.x;
    const int lane = tid & 63;
    const int wid  = tid >> 6;           // 0..7
    const int wm   = (wid >> 2) * 64;    // 0/64
    const int wn   = (wid & 3) * 64;     // 0/64/128/192
    const int m0   = blockIdx.x * BM;

    f32x4 acc[4][4] = {};

    auto stageA = [&](int chunk, char* dst) {
        #pragma unroll
        for (int it = 0; it < 2; ++it) {
            int o   = it * 8192 + tid * 16;
            int r   = o >> 7;                       // row 0..127
            int scb = (o & 127) ^ ((r & 7) << 4);   // pre-swizzled source col byte
            int ga  = m0 + r; if (ga >= M) ga = M - 1;
            GLOAD_LDS16((const char*)A + (size_t)ga * 4608 + (size_t)chunk * 128 + scb, dst + o);
        }
    };
    auto stageB = [&](int chunk) {
        #pragma unroll
        for (int it = 0; it < 4; ++it) {
            int o   = it * 8192 + tid * 16;
            int r   = o >> 7;                       // row 0..255
            int scb = (o & 127) ^ ((r & 7) << 4);
            GLOAD_LDS16((const char*)Bt + (size_t)r * 4608 + (size_t)chunk * 128 + scb, Bb + o);
        }
    };

    // prologue: A(0), B(0), A(1) in flight (8 loads); wait A(0),B(0) done
    stageA(0, Ab0);
    stageB(0);
    stageA(1, Ab1);
    asm volatile("s_waitcnt vmcnt(2)" ::: "memory");
    __builtin_amdgcn_s_barrier();
    __builtin_amdgcn_sched_barrier(0);

    for (int t = 0; t < NCH; ++t) {
        const char* Ac = (t & 1) ? Ab1 : Ab0;
        #pragma unroll
        for (int kk = 0; kk < 2; ++kk) {
            const int koff = kk * 32 + (lane >> 4) * 8;
            bf16x8 af[4], bfr[4];
            #pragma unroll
            for (int i = 0; i < 4; ++i) {
                int ar = wm + i * 16 + (lane & 15);
                af[i] = *(const bf16x8*)(Ac + ((ar * 128 + koff * 2) ^ ((ar & 7) << 4)));
            }
            #pragma unroll
            for (int j = 0; j < 4; ++j) {
                int br = wn + j * 16 + (lane & 15);
                bfr[j] = *(const bf16x8*)(Bb + ((br * 128 + koff * 2) ^ ((br & 7) << 4)));
            }
            #pragma unroll
            for (int i = 0; i < 4; ++i)
                #pragma unroll
                for (int j = 0; j < 4; ++j)
                    acc[i][j] = __builtin_amdgcn_mfma_f32_16x16x32_bf16(af[i], bfr[j], acc[i][j], 0, 0, 0);
        }

        if (t < NCH - 1) {
            __builtin_amdgcn_s_barrier();          // all waves done with B(t), A[t&1]
            __builtin_amdgcn_sched_barrier(0);
            stageB(t + 1);                                   // 4 loads, L2-resident
            int ta = (t + 2 < NCH) ? t + 2 : NCH - 1;        // clamp (data unused)
            stageA(ta, (t & 1) ? Ab1 : Ab0);                 // 2 loads, HBM, 2-iter cover
            asm volatile("s_waitcnt vmcnt(2)" ::: "memory"); // B(t+1),A(t+1) done; A(t+2) flying
            __builtin_amdgcn_s_barrier();
            __builtin_amdgcn_sched_barrier(0);
        }
    }
    asm volatile("s_waitcnt vmcnt(0)" ::: "memory");   // drain clamp-issued extras

    // D mapping: col=lane&15, row=(lane>>4)*4+reg
    const int col = lane & 15;
    const int r0  = (lane >> 4) * 4;
    #pragma unroll
    for (int i = 0; i < 4; ++i) {
        #pragma unroll
        for (int j = 0; j < 4; ++j) {
            int gn = wn + j * 16 + col;
            float bv = bias[gn];
            #pragma unroll
            for (int rr = 0; rr < 4; ++rr) {
                int gm = m0 + wm + i * 16 + r0 + rr;
                if (gm < M) out[(size_t)gm * 256 + gn] = acc[i][j][rr] + bv;
            }
        }
    }
}

// ---------------------------------------------------------------- launch
extern "C" void kernel_launch(void* const* d_in, const int* in_sizes, int n_in,
                              void* d_out, int out_size, void* d_ws, size_t ws_size,
                              hipStream_t stream) {
    const int*   edge_index = (const int*)d_in[0];   // [2][E]
    const float* x          = (const float*)d_in[1]; // [M][256]
    const int*   edge_type  = (const int*)d_in[2];   // [E]
    const float* weight     = (const float*)d_in[3]; // [8][256][256]
    const float* h_bias     = (const float*)d_in[4]; // [256]
    const float* loop_w     = (const float*)d_in[5]; // [256][256]
    float* out = (float*)d_out;

    const int M = in_sizes[1] / 256;   // 50000
    const int E = in_sizes[2];         // 800000

    // workspace: Zcat 230.4MB | wbT 1.18MB | [cnt M | done | done2 | bsum 64] | off M+1 | cur M | recs E
    char* ws = (char*)d_ws;
    size_t off_b = 0;
    unsigned short* Zcat = (unsigned short*)(ws + off_b);
    off_b += (((size_t)M * 2304 * 2) + 255) & ~(size_t)255;
    unsigned short* wbT = (unsigned short*)(ws + off_b);
    off_b += (((size_t)256 * 2304 * 2) + 255) & ~(size_t)255;
    unsigned* cnt = (unsigned*)(ws + off_b);            // cnt[M], done, done2, bsum[64]
    unsigned* done  = cnt + M;
    unsigned* done2 = cnt + M + 1;
    unsigned* bsum  = cnt + M + 2;
    off_b += (((size_t)(M + 2 + 64) * 4) + 255) & ~(size_t)255;
    unsigned* off = (unsigned*)(ws + off_b);
    off_b += (((size_t)(M + 1) * 4) + 255) & ~(size_t)255;
    unsigned* cur = (unsigned*)(ws + off_b);
    off_b += (((size_t)M * 4) + 255) & ~(size_t)255;
    unsigned* recs = (unsigned*)(ws + off_b);

    const int nb = (M + 1023) / 1024;   // 49 scan blocks (all co-resident)
    const int HB = (E + 255) / 256;     // 3125
    const int CB = (M + 3) / 4;         // 12500

    // zero cnt + done + done2 + bsum in one async memset (capture-safe)
    (void)hipMemsetAsync(cnt, 0, (size_t)(M + 2 + 64) * 4, stream);

    // fused: histogram + bf16-x + weight transpose (tiled, coalesced both sides)
    rgcn_prep<<<HB + CB + 144, 256, 0, stream>>>(edge_index, cnt, x, Zcat,
                                                 weight, loop_w, wbT, E, M, HB, CB);
    // fused scan + scatter (one launch)
    rgcn_scan_scatter<<<nb, 1024, 0, stream>>>(cnt, off, cur, done, done2, bsum,
                                               edge_index, edge_type, recs, M, nb, E);

    // per-dst register aggregation -> Zcat[:, 0:2048]
    rgcn_agg<<<2560, 256, 0, stream>>>(recs, off, Zcat, M);

    // single fused GEMM -> out (128x256 tile, 2 resident blocks/CU)
    rgcn_gemm<<<(M + BM - 1) / BM, 512, 0, stream>>>(Zcat, wbT, out, h_bias, M);
}

// Round 16
// 294.877 us; speedup vs baseline: 1.1445x; 1.1445x over previous
//
#include <hip/hip_runtime.h>

typedef __bf16 bf16x8 __attribute__((ext_vector_type(8)));
typedef float f32x4 __attribute__((ext_vector_type(4)));

static __device__ __forceinline__ unsigned short f2bf(float f) {
    unsigned u = __builtin_bit_cast(unsigned, f);
    u += 0x7FFFu + ((u >> 16) & 1u);
    return (unsigned short)(u >> 16);
}
static __device__ __forceinline__ float bf2f(unsigned short h) {
    return __builtin_bit_cast(float, ((unsigned)h) << 16);
}

// async 16B global->LDS (linear LDS dest: wave-uniform base + lane*16)
#define GLOAD_LDS16(g, l)                                              \
    __builtin_amdgcn_global_load_lds(                                  \
        (const __attribute__((address_space(1))) unsigned int*)(g),    \
        (__attribute__((address_space(3))) unsigned int*)(l), 16, 0, 0)

// ---------------------------------------------------------------- fused prep
// blocks [0,HB) hist | [HB, HB+CB) cvt | [HB+CB, HB+CB+144) wbt (tiled transpose)
__global__ __launch_bounds__(256) void rgcn_prep(const int* __restrict__ ei,
                                                 unsigned* __restrict__ cnt,
                                                 const float* __restrict__ x,
                                                 unsigned short* __restrict__ Z,
                                                 const float* __restrict__ w,
                                                 const float* __restrict__ lw,
                                                 unsigned short* __restrict__ wbT,
                                                 int E, int M, int HB, int CB) {
    __shared__ float tile[64][65];
    const int b = blockIdx.x;
    const int t = threadIdx.x;
    if (b < HB) {                     // ---- histogram of dst
        int e = b * 256 + t;
        if (e < E) atomicAdd(&cnt[ei[E + e]], 1u);
    } else if (b < HB + CB) {         // ---- bf16 x -> Zcat[:, 2048:2304]
        int wv = ((b - HB) * 256 + t) >> 6;
        int lane = t & 63;
        if (wv < M) {
            float4 v = *(const float4*)(x + (size_t)wv * 256 + lane * 4);
            ushort4 o;
            o.x = f2bf(v.x); o.y = f2bf(v.y); o.z = f2bf(v.z); o.w = f2bf(v.w);
            *(ushort4*)(Z + (size_t)wv * 2304 + 2048 + lane * 4) = o;
        }
    } else {                          // ---- wbT 64x64 tile transpose (144 blocks)
        const int bb = b - HB - CB;
        const float* src;
        int kt, nt_, kcb;
        if (bb < 128) {               // weight[r]: 16 tiles each
            int r = bb >> 4, tl = bb & 15;
            kt = (tl >> 2) * 64; nt_ = (tl & 3) * 64;
            src = w + (size_t)r * 65536;
            kcb = r * 256 + kt;
        } else {                      // loop_w: 16 tiles
            int tl = bb - 128;
            kt = (tl >> 2) * 64; nt_ = (tl & 3) * 64;
            src = lw;
            kcb = 2048 + kt;
        }
        // coalesced load: 64 rows (k) x 64 cols (n)
        {
            int row = t >> 4, c4 = (t & 15) * 4;
            #pragma unroll
            for (int p = 0; p < 4; ++p) {
                int rr = row + p * 16;
                float4 v = *(const float4*)(src + (size_t)(kt + rr) * 256 + nt_ + c4);
                tile[rr][c4] = v.x; tile[rr][c4 + 1] = v.y;
                tile[rr][c4 + 2] = v.z; tile[rr][c4 + 3] = v.w;
            }
        }
        __syncthreads();
        // coalesced write: 64 rows (n) x 64 cols (kc), 16 kc per thread
        {
            const float s = 0.70710678118654752f;
            int nn = t >> 2, ko = (t & 3) * 16;
            unsigned short* dst = wbT + (size_t)(nt_ + nn) * 2304 + kcb + ko;
            #pragma unroll
            for (int q = 0; q < 4; ++q) {
                ushort4 o_;
                o_.x = f2bf(tile[ko + q * 4 + 0][nn] * s);
                o_.y = f2bf(tile[ko + q * 4 + 1][nn] * s);
                o_.z = f2bf(tile[ko + q * 4 + 2][nn] * s);
                o_.w = f2bf(tile[ko + q * 4 + 3][nn] * s);
                *(ushort4*)(dst + q * 4) = o_;
            }
        }
    }
}

// ---------------------------------------------------------------- single-kernel scan
__global__ __launch_bounds__(1024) void rgcn_scan_all(const unsigned* __restrict__ cnt,
                                                      unsigned* __restrict__ off,
                                                      unsigned* __restrict__ cur,
                                                      unsigned* __restrict__ done,
                                                      unsigned* __restrict__ bsum,
                                                      int n, int nb) {
    __shared__ unsigned wsum[16];
    __shared__ unsigned bpre_s;
    const int t = threadIdx.x, lane = t & 63, wv = t >> 6;
    const int b = blockIdx.x;
    int i = b * 1024 + t;
    unsigned v = (i < n) ? cnt[i] : 0;
    unsigned s = v;
    #pragma unroll
    for (int d = 1; d < 64; d <<= 1) {
        unsigned u = __shfl_up(s, d, 64);
        if (lane >= d) s += u;
    }
    if (lane == 63) wsum[wv] = s;
    __syncthreads();
    if (wv == 0) {
        unsigned bb = (lane < 16) ? wsum[lane] : 0;
        unsigned sb = bb;
        #pragma unroll
        for (int d = 1; d < 16; d <<= 1) {
            unsigned u = __shfl_up(sb, d, 64);
            if (lane >= d) sb += u;
        }
        if (lane < 16) wsum[lane] = sb - bb;       // exclusive wave prefix
        if (lane == 15) {                          // post block total (release)
            atomicExch(&bsum[b], sb);
            __threadfence();
            atomicAdd(done, 1u);
        }
    }
    __syncthreads();
    if (t == 0) {                                  // spin until all blocks posted
        while (atomicAdd(done, 0u) < (unsigned)nb) __builtin_amdgcn_s_sleep(8);
    }
    __syncthreads();
    if (wv == 0) {                                 // cross-block exclusive prefix
        unsigned bv = (lane < nb) ? atomicAdd(&bsum[lane], 0u) : 0;
        unsigned sp = bv;
        #pragma unroll
        for (int d = 1; d < 64; d <<= 1) {
            unsigned u = __shfl_up(sp, d, 64);
            if (lane >= d) sp += u;
        }
        if (lane == b) bpre_s = sp - bv;
        if (b == 0 && lane == nb - 1) off[n] = sp; // grand total = E
    }
    __syncthreads();
    unsigned base = bpre_s + wsum[wv];
    if (i < n) {
        unsigned o = base + (s - v);
        off[i] = o;
        cur[i] = o;
    }
}

// scatter packed records (src | rel<<16) into dst-sorted order
__global__ __launch_bounds__(256) void rgcn_scatter(const int* __restrict__ ei,
                                                    const int* __restrict__ et,
                                                    unsigned* __restrict__ cur,
                                                    unsigned* __restrict__ recs, int E) {
    int e = blockIdx.x * 256 + threadIdx.x;
    if (e < E) {
        int dst = ei[E + e];
        unsigned p = atomicAdd(&cur[dst], 1u);
        recs[p] = (unsigned)ei[e] | ((unsigned)et[e] << 16);
    }
}

// ---------------------------------------------------------------- aggregation
// one wave per dst node (grid-stride). Lane l loads recs[o0+l]; per-edge records
// via __shfl; ushort4 gathers in 16-deep batches. (127us, throughput-pinned at
// ~3.1 TB/s across 4 structural variants — structural limit.)
__global__ __launch_bounds__(256) void rgcn_agg(const unsigned* __restrict__ recs,
                                                const unsigned* __restrict__ off,
                                                unsigned short* __restrict__ Z, int M) {
    const int gw0  = (blockIdx.x * 256 + threadIdx.x) >> 6;
    const int nw   = (gridDim.x * 256) >> 6;
    const int lane = threadIdx.x & 63;
    const unsigned short* Zx = Z + 2048 + lane * 4;   // gather base (x cols)

#define GATHER(rr) (*(const ushort4*)(Zx + (size_t)((rr) & 0xFFFFu) * 2304))
#define ACCUM(rec, v_)                                                                 \
    {                                                                                  \
        f32x4 fv;                                                                      \
        fv[0] = bf2f(v_.x); fv[1] = bf2f(v_.y); fv[2] = bf2f(v_.z); fv[3] = bf2f(v_.w);\
        switch ((rec) >> 16) {                                                         \
            case 0: a0 += fv; break; case 1: a1 += fv; break;                          \
            case 2: a2 += fv; break; case 3: a3 += fv; break;                          \
            case 4: a4 += fv; break; case 5: a5 += fv; break;                          \
            case 6: a6 += fv; break; default: a7 += fv; break;                         \
        }                                                                              \
    }

    for (int w = gw0; w < M; w += nw) {
        const unsigned o0 = off[w], o1 = off[w + 1];
        f32x4 a0 = {}, a1 = {}, a2 = {}, a3 = {}, a4 = {}, a5 = {}, a6 = {}, a7 = {};

        for (unsigned base = o0; base < o1; base += 64) {
            const unsigned wdeg = (o1 - base < 64u) ? (o1 - base) : 64u;
            const unsigned myrec = ((unsigned)lane < wdeg) ? recs[base + lane] : 0u;

            unsigned j = 0;
            for (; j + 16 <= wdeg; j += 16) {
                unsigned rr[16];
                #pragma unroll
                for (int u = 0; u < 16; ++u) rr[u] = __shfl(myrec, (int)(j + u), 64);
                ushort4 vv[16];
                #pragma unroll
                for (int u = 0; u < 16; ++u) vv[u] = GATHER(rr[u]);
                #pragma unroll
                for (int u = 0; u < 16; ++u) ACCUM(rr[u], vv[u]);
            }
            for (; j + 4 <= wdeg; j += 4) {
                unsigned rr[4];
                #pragma unroll
                for (int u = 0; u < 4; ++u) rr[u] = __shfl(myrec, (int)(j + u), 64);
                ushort4 vv[4];
                #pragma unroll
                for (int u = 0; u < 4; ++u) vv[u] = GATHER(rr[u]);
                #pragma unroll
                for (int u = 0; u < 4; ++u) ACCUM(rr[u], vv[u]);
            }
            for (; j < wdeg; ++j) {
                unsigned r_ = __shfl(myrec, (int)j, 64);
                ushort4 v_ = GATHER(r_);
                ACCUM(r_, v_);
            }
        }

        unsigned short* zr = Z + (size_t)w * 2304 + lane * 4;
#define ST(rr_, ax)                                                                    \
        {                                                                              \
            ushort4 o_;                                                                \
            o_.x = f2bf(ax[0]); o_.y = f2bf(ax[1]);                                    \
            o_.z = f2bf(ax[2]); o_.w = f2bf(ax[3]);                                    \
            *(ushort4*)(zr + rr_ * 256) = o_;                                          \
        }
        ST(0, a0) ST(1, a1) ST(2, a2) ST(3, a3) ST(4, a4) ST(5, a5) ST(6, a6) ST(7, a7)
#undef ST
    }
#undef GATHER
#undef ACCUM
}

// ---------------------------------------------------------------- GEMM v5 (round-12 verified)
// out[M x 256] = Zcat[M x 2304] @ wbT^T + bias
// 128x256 tile, 512 threads (8 waves, 64x64 each). LDS 64KB = A dbuf 2x16KB +
// B single 32KB -> 2 resident blocks/CU. Counted-vmcnt pipeline:
//   compute(t) -> bar -> stage B(t+1)(L2,4ld) + A(t+2)(HBM,2ld) -> vmcnt(2) -> bar
#define BM 128
#define BK 64
#define NCH 36   // 2304 / 64

__global__ __launch_bounds__(512, 4) void rgcn_gemm(
    const unsigned short* __restrict__ A,    // Zcat [M][2304]
    const unsigned short* __restrict__ Bt,   // wbT  [256][2304]
    float* __restrict__ out,                 // [M][256]
    const float* __restrict__ bias,          // [256]
    int M)
{
    __shared__ char lds[16384 * 2 + 32768];  // A0 | A1 | B
    char* Ab0 = lds;
    char* Ab1 = lds + 16384;
    char* Bb  = lds + 32768;

    const int tid  = threadIdx.x;
    const int lane = tid & 63;
    const int wid  = tid >> 6;           // 0..7
    const int wm   = (wid >> 2) * 64;    // 0/64
    const int wn   = (wid & 3) * 64;     // 0/64/128/192
    const int m0   = blockIdx.x * BM;

    f32x4 acc[4][4] = {};

    auto stageA = [&](int chunk, char* dst) {
        #pragma unroll
        for (int it = 0; it < 2; ++it) {
            int o   = it * 8192 + tid * 16;
            int r   = o >> 7;                       // row 0..127
            int scb = (o & 127) ^ ((r & 7) << 4);   // pre-swizzled source col byte
            int ga  = m0 + r; if (ga >= M) ga = M - 1;
            GLOAD_LDS16((const char*)A + (size_t)ga * 4608 + (size_t)chunk * 128 + scb, dst + o);
        }
    };
    auto stageB = [&](int chunk) {
        #pragma unroll
        for (int it = 0; it < 4; ++it) {
            int o   = it * 8192 + tid * 16;
            int r   = o >> 7;                       // row 0..255
            int scb = (o & 127) ^ ((r & 7) << 4);
            GLOAD_LDS16((const char*)Bt + (size_t)r * 4608 + (size_t)chunk * 128 + scb, Bb + o);
        }
    };

    // prologue: A(0), B(0), A(1) in flight (8 loads); wait A(0),B(0) done
    stageA(0, Ab0);
    stageB(0);
    stageA(1, Ab1);
    asm volatile("s_waitcnt vmcnt(2)" ::: "memory");
    __builtin_amdgcn_s_barrier();
    __builtin_amdgcn_sched_barrier(0);

    for (int t = 0; t < NCH; ++t) {
        const char* Ac = (t & 1) ? Ab1 : Ab0;
        #pragma unroll
        for (int kk = 0; kk < 2; ++kk) {
            const int koff = kk * 32 + (lane >> 4) * 8;
            bf16x8 af[4], bfr[4];
            #pragma unroll
            for (int i = 0; i < 4; ++i) {
                int ar = wm + i * 16 + (lane & 15);
                af[i] = *(const bf16x8*)(Ac + ((ar * 128 + koff * 2) ^ ((ar & 7) << 4)));
            }
            #pragma unroll
            for (int j = 0; j < 4; ++j) {
                int br = wn + j * 16 + (lane & 15);
                bfr[j] = *(const bf16x8*)(Bb + ((br * 128 + koff * 2) ^ ((br & 7) << 4)));
            }
            #pragma unroll
            for (int i = 0; i < 4; ++i)
                #pragma unroll
                for (int j = 0; j < 4; ++j)
                    acc[i][j] = __builtin_amdgcn_mfma_f32_16x16x32_bf16(af[i], bfr[j], acc[i][j], 0, 0, 0);
        }

        if (t < NCH - 1) {
            __builtin_amdgcn_s_barrier();          // all waves done with B(t), A[t&1]
            __builtin_amdgcn_sched_barrier(0);
            stageB(t + 1);                                   // 4 loads, L2-resident
            int ta = (t + 2 < NCH) ? t + 2 : NCH - 1;        // clamp (data unused)
            stageA(ta, (t & 1) ? Ab1 : Ab0);                 // 2 loads, HBM, 2-iter cover
            asm volatile("s_waitcnt vmcnt(2)" ::: "memory"); // B(t+1),A(t+1) done; A(t+2) flying
            __builtin_amdgcn_s_barrier();
            __builtin_amdgcn_sched_barrier(0);
        }
    }
    asm volatile("s_waitcnt vmcnt(0)" ::: "memory");   // drain clamp-issued extras

    // D mapping: col=lane&15, row=(lane>>4)*4+reg
    const int col = lane & 15;
    const int r0  = (lane >> 4) * 4;
    #pragma unroll
    for (int i = 0; i < 4; ++i) {
        #pragma unroll
        for (int j = 0; j < 4; ++j) {
            int gn = wn + j * 16 + col;
            float bv = bias[gn];
            #pragma unroll
            for (int rr = 0; rr < 4; ++rr) {
                int gm = m0 + wm + i * 16 + r0 + rr;
                if (gm < M) out[(size_t)gm * 256 + gn] = acc[i][j][rr] + bv;
            }
        }
    }
}

// ---------------------------------------------------------------- launch
extern "C" void kernel_launch(void* const* d_in, const int* in_sizes, int n_in,
                              void* d_out, int out_size, void* d_ws, size_t ws_size,
                              hipStream_t stream) {
    const int*   edge_index = (const int*)d_in[0];   // [2][E]
    const float* x          = (const float*)d_in[1]; // [M][256]
    const int*   edge_type  = (const int*)d_in[2];   // [E]
    const float* weight     = (const float*)d_in[3]; // [8][256][256]
    const float* h_bias     = (const float*)d_in[4]; // [256]
    const float* loop_w     = (const float*)d_in[5]; // [256][256]
    float* out = (float*)d_out;

    const int M = in_sizes[1] / 256;   // 50000
    const int E = in_sizes[2];         // 800000

    // workspace: Zcat 230.4MB | wbT 1.18MB | [cnt M | done | done2 | bsum 64] | off M+1 | cur M | recs E
    char* ws = (char*)d_ws;
    size_t off_b = 0;
    unsigned short* Zcat = (unsigned short*)(ws + off_b);
    off_b += (((size_t)M * 2304 * 2) + 255) & ~(size_t)255;
    unsigned short* wbT = (unsigned short*)(ws + off_b);
    off_b += (((size_t)256 * 2304 * 2) + 255) & ~(size_t)255;
    unsigned* cnt = (unsigned*)(ws + off_b);            // cnt[M], done, done2, bsum[64]
    unsigned* done  = cnt + M;
    unsigned* bsum  = cnt + M + 2;
    off_b += (((size_t)(M + 2 + 64) * 4) + 255) & ~(size_t)255;
    unsigned* off = (unsigned*)(ws + off_b);
    off_b += (((size_t)(M + 1) * 4) + 255) & ~(size_t)255;
    unsigned* cur = (unsigned*)(ws + off_b);
    off_b += (((size_t)M * 4) + 255) & ~(size_t)255;
    unsigned* recs = (unsigned*)(ws + off_b);

    const int nb = (M + 1023) / 1024;   // 49 scan blocks (all co-resident)
    const int HB = (E + 255) / 256;     // 3125
    const int CB = (M + 3) / 4;         // 12500

    // zero cnt + done + bsum in one async memset (capture-safe)
    (void)hipMemsetAsync(cnt, 0, (size_t)(M + 2 + 64) * 4, stream);

    // fused: histogram + bf16-x + weight transpose (tiled, coalesced both sides)
    rgcn_prep<<<HB + CB + 144, 256, 0, stream>>>(edge_index, cnt, x, Zcat,
                                                 weight, loop_w, wbT, E, M, HB, CB);
    // single-kernel hierarchical scan
    rgcn_scan_all<<<nb, 1024, 0, stream>>>(cnt, off, cur, done, bsum, M, nb);
    // scatter with full thread-level parallelism (800K threads)
    rgcn_scatter<<<(E + 255) / 256, 256, 0, stream>>>(edge_index, edge_type, cur, recs, E);

    // per-dst register aggregation -> Zcat[:, 0:2048]
    rgcn_agg<<<2560, 256, 0, stream>>>(recs, off, Zcat, M);

    // single fused GEMM -> out (128x256 tile, 2 resident blocks/CU)
    rgcn_gemm<<<(M + BM - 1) / BM, 512, 0, stream>>>(Zcat, wbT, out, h_bias, M);
}